// Round 1
// baseline (274.940 us; speedup 1.0000x reference)
//
#include <hip/hip_runtime.h>
#include <hip/hip_bf16.h>

// Problem: B=256, T=64, A=32, H=512, E=32
#define NB 256
#define NT 64
#define NA 32
#define NH 512
#define NE 32
#define MAXTILES 144   // max sum_e ceil(count_e/2) = 128 + 16

typedef short short8 __attribute__((ext_vector_type(8)));
typedef unsigned short ushort8v __attribute__((ext_vector_type(8)));
typedef float f32x4 __attribute__((ext_vector_type(4)));

__device__ __forceinline__ unsigned short f2bf(float f) {
  unsigned int u = __float_as_uint(f);
  u += 0x7FFFu + ((u >> 16) & 1u);   // round-to-nearest-even
  return (unsigned short)(u >> 16);
}

// ---------------------------------------------------------------------------
// Kernel A: group samples by expert; build tiles of 2 same-expert samples.
// tiles[3*t] = expert, tiles[3*t+1] = sample0, tiles[3*t+2] = sample1 or -1
// ---------------------------------------------------------------------------
__global__ __launch_bounds__(256) void groupk(const int* __restrict__ cat,
                                              int* __restrict__ tiles,
                                              int* __restrict__ ntiles_out) {
  __shared__ int cnt[NE], off[NE], cur[NE];
  __shared__ int order[NB];
  int tid = threadIdx.x;
  if (tid < NE) cnt[tid] = 0;
  __syncthreads();
  int e = cat[tid];
  atomicAdd(&cnt[e], 1);
  __syncthreads();
  if (tid == 0) {
    int s = 0;
    for (int i = 0; i < NE; i++) { off[i] = s; cur[i] = s; s += cnt[i]; }
  }
  __syncthreads();
  int p = atomicAdd(&cur[e], 1);
  order[p] = tid;
  __syncthreads();
  if (tid == 0) {
    int nt = 0;
    for (int i = 0; i < NE; i++) {
      for (int j = 0; j < cnt[i]; j += 2) {
        tiles[3 * nt + 0] = i;
        tiles[3 * nt + 1] = order[off[i] + j];
        tiles[3 * nt + 2] = (j + 1 < cnt[i]) ? order[off[i] + j + 1] : -1;
        nt++;
      }
    }
    *ntiles_out = nt;
  }
}

// ---------------------------------------------------------------------------
// Kernel B: build x = concat(a_emb, tau) as bf16, shape (B*T, 1024).
// blockIdx.x = nt (0..3: a_emb col tiles of 128; 4..7: tau col tiles of 128)
// blockIdx.y = sample b
// ---------------------------------------------------------------------------
__global__ __launch_bounds__(256) void buildx_kernel(
    const float* __restrict__ actions, const int* __restrict__ timesteps,
    const int* __restrict__ cat_ids, const float* __restrict__ W1,
    const float* __restrict__ b1, unsigned short* __restrict__ X) {
  int b = blockIdx.y;
  int nt = blockIdx.x;
  int tid = threadIdx.x;

  if (nt >= 4) {
    // tau: x[b,t,512+c] = sin(t_b * f_c) for c<256 else cos(t_b * f_{c-256})
    float t_val = (float)timesteps[b];
    int c = (nt - 4) * 128 + (tid & 127);
    int rp = tid >> 7;
    int i_f = c & 255;
    const float kLog = 0.035977893400931146f;  // ln(10000)/256
    float f = expf(-(float)i_f * kLog);
    float ang = t_val * f;
    float v = (c < 256) ? sinf(ang) : cosf(ang);
    unsigned short us = f2bf(v);
    unsigned short* dst = X + (size_t)(b * NT) * 1024 + 512 + c;
    for (int t = rp; t < NT; t += 2) dst[(size_t)t * 1024] = us;
    return;
  }

  // a_emb tile: 64 rows x 128 cols, K=32 (single MFMA k-step)
  __shared__ unsigned short As[64 * 40];    // [row][k], stride 40 (pad)
  __shared__ unsigned short Bs[128 * 40];   // [n][k], stride 40
  int e = cat_ids[b];
  int n0 = nt * 128;

  {  // stage A: actions[b] 64x32 fp32 -> bf16
    int row = tid >> 2, seg = tid & 3;
    const float* src = actions + (size_t)(b * NT + row) * NA + seg * 8;
    float4 v0 = *(const float4*)(src);
    float4 v1 = *(const float4*)(src + 4);
    ushort8v t;
    t[0] = f2bf(v0.x); t[1] = f2bf(v0.y); t[2] = f2bf(v0.z); t[3] = f2bf(v0.w);
    t[4] = f2bf(v1.x); t[5] = f2bf(v1.y); t[6] = f2bf(v1.z); t[7] = f2bf(v1.w);
    *(ushort8v*)(&As[row * 40 + seg * 8]) = t;
  }
  {  // stage B: W1[e][k][n] fp32 -> Bs[n][k] bf16
    int n = tid & 127, kh = tid >> 7;
    const float* src = W1 + ((size_t)e * NA + kh * 16) * NH + n0 + n;
    ushort8v p0, p1;
#pragma unroll
    for (int kk = 0; kk < 8; kk++) p0[kk] = f2bf(src[(size_t)kk * NH]);
#pragma unroll
    for (int kk = 0; kk < 8; kk++) p1[kk] = f2bf(src[(size_t)(kk + 8) * NH]);
    *(ushort8v*)(&Bs[n * 40 + kh * 16]) = p0;
    *(ushort8v*)(&Bs[n * 40 + kh * 16 + 8]) = p1;
  }
  __syncthreads();

  int w = tid >> 6, l = tid & 63;
  int lrow = l & 15, koff = (l >> 4) * 8;
  f32x4 zero = {0.0f, 0.0f, 0.0f, 0.0f};
  short8 af = *(short8*)(&As[(w * 16 + lrow) * 40 + koff]);
  f32x4 acc[8];
#pragma unroll
  for (int ni = 0; ni < 8; ni++) {
    short8 bfv = *(short8*)(&Bs[(ni * 16 + lrow) * 40 + koff]);
    acc[ni] = __builtin_amdgcn_mfma_f32_16x16x32_bf16(af, bfv, zero, 0, 0, 0);
  }
#pragma unroll
  for (int ni = 0; ni < 8; ni++) {
    int col = n0 + ni * 16 + lrow;
    float bv = b1[(size_t)e * NH + col];
#pragma unroll
    for (int r = 0; r < 4; r++) {
      int row = w * 16 + (l >> 4) * 4 + r;
      X[(size_t)(b * NT + row) * 1024 + col] = f2bf(acc[ni][r] + bv);
    }
  }
}

// ---------------------------------------------------------------------------
// Grouped GEMM: Y[tile rows, n0:n0+128] = act(X @ W[e] + bias[e])
// BM=128 (2 samples), BN=128, BK=32, 4 waves in 2x2, each wave 4x4 MFMA tiles.
// W is fp32 row-major (K,512) per expert; converted to bf16 while staging.
// ---------------------------------------------------------------------------
template <int KSTEPS, int LDX, bool SWISH, bool OUT_BF16>
__global__ __launch_bounds__(256) void gemm_kernel(
    const unsigned short* __restrict__ X, const float* __restrict__ W,
    const float* __restrict__ bias, void* __restrict__ Yv,
    const int* __restrict__ tiles, const int* __restrict__ pntiles) {
  int ti = blockIdx.y;
  if (ti >= *pntiles) return;
  const int K = KSTEPS * 32;
  int n0 = blockIdx.x * 128;
  int e = tiles[3 * ti], s0 = tiles[3 * ti + 1], s1 = tiles[3 * ti + 2];

  __shared__ unsigned short As[128 * 40];   // [row][k] stride 40
  __shared__ unsigned short Bs[128 * 40];   // [n][k]  stride 40

  int tid = threadIdx.x;
  int w = tid >> 6, l = tid & 63;
  int wr = w >> 1, wc = w & 1;
  int lrow = l & 15, koff = (l >> 4) * 8;

  f32x4 acc[4][4];
#pragma unroll
  for (int mi = 0; mi < 4; mi++)
#pragma unroll
    for (int ni = 0; ni < 4; ni++) acc[mi][ni] = (f32x4){0.f, 0.f, 0.f, 0.f};

  int bn = tid & 127, bkh = tid >> 7;
  const float* wbase = W + (size_t)e * K * NH + (size_t)(bkh * 16) * NH + n0 + bn;

  for (int ks = 0; ks < KSTEPS; ks++) {
    int k0 = ks * 32;
    __syncthreads();
    // stage A: 128 rows x 32 k of bf16 activations
#pragma unroll
    for (int it = 0; it < 2; it++) {
      int u = tid + it * 256;
      int row = u >> 2, seg = u & 3;
      int s = (row < 64) ? s0 : s1;
      if (s >= 0) {
        uint4 v = *(const uint4*)(X + (size_t)(s * NT + (row & 63)) * LDX + k0 + seg * 8);
        *(uint4*)(&As[row * 40 + seg * 8]) = v;
      }
    }
    // stage B: W[e][k0:k0+32][n0:n0+128] fp32 -> Bs[n][k] bf16
    {
      const float* src = wbase + (size_t)k0 * NH;
      ushort8v p0, p1;
#pragma unroll
      for (int kk = 0; kk < 8; kk++) p0[kk] = f2bf(src[(size_t)kk * NH]);
#pragma unroll
      for (int kk = 0; kk < 8; kk++) p1[kk] = f2bf(src[(size_t)(kk + 8) * NH]);
      *(ushort8v*)(&Bs[bn * 40 + bkh * 16]) = p0;
      *(ushort8v*)(&Bs[bn * 40 + bkh * 16 + 8]) = p1;
    }
    __syncthreads();

    short8 af[4], bfv[4];
#pragma unroll
    for (int mi = 0; mi < 4; mi++)
      af[mi] = *(short8*)(&As[(wr * 64 + mi * 16 + lrow) * 40 + koff]);
#pragma unroll
    for (int ni = 0; ni < 4; ni++)
      bfv[ni] = *(short8*)(&Bs[(wc * 64 + ni * 16 + lrow) * 40 + koff]);
#pragma unroll
    for (int mi = 0; mi < 4; mi++)
#pragma unroll
      for (int ni = 0; ni < 4; ni++)
        acc[mi][ni] = __builtin_amdgcn_mfma_f32_16x16x32_bf16(af[mi], bfv[ni], acc[mi][ni], 0, 0, 0);
  }

  // epilogue: bias (+swish), store
  int s = (wr == 0) ? s0 : s1;
  if (s < 0) return;
#pragma unroll
  for (int ni = 0; ni < 4; ni++) {
    int col = n0 + wc * 64 + ni * 16 + lrow;
    float bv = bias[(size_t)e * NH + col];
#pragma unroll
    for (int mi = 0; mi < 4; mi++) {
      int rowl = mi * 16 + (l >> 4) * 4;
#pragma unroll
      for (int r = 0; r < 4; r++) {
        int row = rowl + r;
        float v = acc[mi][ni][r] + bv;
        if (SWISH) v = v / (1.0f + expf(-v));
        size_t off = (size_t)(s * NT + row) * NH + col;
        if (OUT_BF16)
          ((unsigned short*)Yv)[off] = f2bf(v);
        else
          ((float*)Yv)[off] = v;
      }
    }
  }
}

// ---------------------------------------------------------------------------
extern "C" void kernel_launch(void* const* d_in, const int* in_sizes, int n_in,
                              void* d_out, int out_size, void* d_ws, size_t ws_size,
                              hipStream_t stream) {
  const float* actions   = (const float*)d_in[0];   // (256,64,32) f32
  const int*   timesteps = (const int*)d_in[1];     // (256,) i32
  const int*   cat_ids   = (const int*)d_in[2];     // (256,) i32
  const float* W1 = (const float*)d_in[3];          // (32,32,512)
  const float* b1 = (const float*)d_in[4];          // (32,512)
  const float* W2 = (const float*)d_in[5];          // (32,1024,512)
  const float* b2 = (const float*)d_in[6];          // (32,512)
  const float* W3 = (const float*)d_in[7];          // (32,512,512)
  const float* b3 = (const float*)d_in[8];          // (32,512)

  // ws layout: X bf16 (16384,1024) = 32MB | H bf16 (16384,512) = 16MB | tiles
  unsigned short* X  = (unsigned short*)d_ws;
  unsigned short* Hb = (unsigned short*)((char*)d_ws + (size_t)33554432);
  int* tiles  = (int*)((char*)d_ws + (size_t)33554432 + 16777216);
  int* ntiles = tiles + 3 * MAXTILES;

  groupk<<<1, 256, 0, stream>>>(cat_ids, tiles, ntiles);
  buildx_kernel<<<dim3(8, NB), 256, 0, stream>>>(actions, timesteps, cat_ids, W1, b1, X);
  gemm_kernel<32, 1024, true, true><<<dim3(4, MAXTILES), 256, 0, stream>>>(
      X, W2, b2, (void*)Hb, tiles, ntiles);
  gemm_kernel<16, 512, false, false><<<dim3(4, MAXTILES), 256, 0, stream>>>(
      Hb, W3, b3, d_out, tiles, ntiles);
}

// Round 2
// 252.693 us; speedup vs baseline: 1.0880x; 1.0880x over previous
//
#include <hip/hip_runtime.h>
#include <hip/hip_bf16.h>

// Problem: B=256, T=64, A=32, H=512, E=32
#define NB 256
#define NT 64
#define NA 32
#define NH 512
#define NE 32
#define MAXTILES 144   // max sum_e ceil(count_e/2) = 128 + 16

typedef short short8 __attribute__((ext_vector_type(8)));
typedef unsigned short ushort8v __attribute__((ext_vector_type(8)));
typedef float f32x4 __attribute__((ext_vector_type(4)));

__device__ __forceinline__ unsigned short f2bf(float f) {
  unsigned int u = __float_as_uint(f);
  u += 0x7FFFu + ((u >> 16) & 1u);   // round-to-nearest-even
  return (unsigned short)(u >> 16);
}

// async global->LDS, 16B per lane; lds dest = wave-uniform base + lane*16
__device__ __forceinline__ void gl2lds16(const void* g, void* l) {
  __builtin_amdgcn_global_load_lds(
      (const __attribute__((address_space(1))) unsigned int*)g,
      (__attribute__((address_space(3))) unsigned int*)l, 16, 0, 0);
}

// ---------------------------------------------------------------------------
// groupk: bucket samples by expert; tiles of 2 same-expert samples.
// ---------------------------------------------------------------------------
__global__ __launch_bounds__(256) void groupk(const int* __restrict__ cat,
                                              int* __restrict__ tiles,
                                              int* __restrict__ ntiles_out) {
  __shared__ int cnt[NE], off[NE], cur[NE];
  __shared__ int order[NB];
  int tid = threadIdx.x;
  if (tid < NE) cnt[tid] = 0;
  __syncthreads();
  int e = cat[tid];
  atomicAdd(&cnt[e], 1);
  __syncthreads();
  if (tid == 0) {
    int s = 0;
    for (int i = 0; i < NE; i++) { off[i] = s; cur[i] = s; s += cnt[i]; }
  }
  __syncthreads();
  int p = atomicAdd(&cur[e], 1);
  order[p] = tid;
  __syncthreads();
  if (tid == 0) {
    int nt = 0;
    for (int i = 0; i < NE; i++) {
      for (int j = 0; j < cnt[i]; j += 2) {
        tiles[3 * nt + 0] = i;
        tiles[3 * nt + 1] = order[off[i] + j];
        tiles[3 * nt + 2] = (j + 1 < cnt[i]) ? order[off[i] + j + 1] : -1;
        nt++;
      }
    }
    *ntiles_out = nt;
  }
}

// ---------------------------------------------------------------------------
// prep: W fp32 [e][K][N=512] -> Wt bf16 [e][N][K]  (transpose + convert)
// grid: (N/64, ceil(K/64), E), 64x64 tiles through LDS (stride 66 = conflict-lite)
// ---------------------------------------------------------------------------
__global__ __launch_bounds__(256) void prep_kernel(const float* __restrict__ W,
                                                   unsigned short* __restrict__ Wt,
                                                   int K) {
  __shared__ float S[64 * 66];
  int e = blockIdx.z;
  int nt = blockIdx.x * 64;
  int kt = blockIdx.y * 64;
  int TK = (K - kt) < 64 ? (K - kt) : 64;   // 64 or 32 (W1)
  int tid = threadIdx.x;
  int units = TK * 32;  // float2 units
  for (int u = tid; u < units; u += 256) {
    int k = u >> 5, c = u & 31;
    float2 v = *(const float2*)(W + ((size_t)e * K + kt + k) * NH + nt + 2 * c);
    *(float2*)(&S[k * 66 + 2 * c]) = v;
  }
  __syncthreads();
  int csh = (TK == 64) ? 3 : 2;  // chunks per row = TK/8
  int CHm = (1 << csh) - 1;
  int wunits = 64 << csh;
  for (int u = tid; u < wunits; u += 256) {
    int n = u >> csh, c = u & CHm;
    ushort8v pk;
#pragma unroll
    for (int j = 0; j < 8; j++) pk[j] = f2bf(S[(c * 8 + j) * 66 + n]);
    *(ushort8v*)(Wt + ((size_t)e * NH + nt + n) * K + kt + c * 8) = pk;
  }
}

// ---------------------------------------------------------------------------
// buildx2: per (sample b, half h): a_emb cols h*256..h*256+255 -> Xa (bf16),
// tau (per-sample constant over T!) -> Xt[b][512]. LDS-transposed uint4 stores.
// ---------------------------------------------------------------------------
__global__ __launch_bounds__(256) void buildx2_kernel(
    const float* __restrict__ actions, const int* __restrict__ timesteps,
    const int* __restrict__ cat_ids, const unsigned short* __restrict__ Wt1,
    const float* __restrict__ b1, unsigned short* __restrict__ Xa,
    unsigned short* __restrict__ Xt) {
  __shared__ __align__(16) unsigned char smem[16384 + 5120 + 512 + 33792];
  unsigned short* Ws  = (unsigned short*)smem;                        // [256][32] swizzled
  unsigned short* As  = (unsigned short*)(smem + 16384);              // [64][40]
  unsigned short* tau = (unsigned short*)(smem + 16384 + 5120);       // [256]
  unsigned short* Ts  = (unsigned short*)(smem + 16384 + 5120 + 512); // [64][264]

  int b = blockIdx.y, h = blockIdx.x;
  int tid = threadIdx.x;
  int e = cat_ids[b];

  {  // async stage Wt1[e][h*256 .. +256][0..32] -> Ws (chunk swizzle ^((n>>1)&3))
    const unsigned short* wsrc = Wt1 + ((size_t)e * NH + h * 256) * NA;
#pragma unroll
    for (int j = 0; j < 4; j++) {
      int u = j * 256 + tid;
      int n = u >> 2, p = u & 3;
      int ch = p ^ ((n >> 1) & 3);
      gl2lds16(wsrc + (size_t)n * NA + ch * 8,
               Ws + (size_t)(j * 256 + (tid & 448)) * 8);
    }
  }
  {  // stage actions (64x32 f32 -> bf16), padded stride 40
    int row = tid >> 2, seg = tid & 3;
    const float* src = actions + (size_t)(b * NT + row) * NA + seg * 8;
    float4 v0 = *(const float4*)(src);
    float4 v1 = *(const float4*)(src + 4);
    ushort8v t;
    t[0] = f2bf(v0.x); t[1] = f2bf(v0.y); t[2] = f2bf(v0.z); t[3] = f2bf(v0.w);
    t[4] = f2bf(v1.x); t[5] = f2bf(v1.y); t[6] = f2bf(v1.z); t[7] = f2bf(v1.w);
    *(ushort8v*)(&As[row * 40 + seg * 8]) = t;
  }
  {  // tau: h==0 -> sin(f_tid * t), h==1 -> cos(f_tid * t)
    float tv = (float)timesteps[b];
    const float kLog = 0.035977893400931146f;  // ln(10000)/256
    float f = expf(-(float)tid * kLog);
    float ang = tv * f;
    float v = (h == 0) ? sinf(ang) : cosf(ang);
    tau[tid] = f2bf(v);
  }
  __syncthreads();

  int w = tid >> 6, l = tid & 63;
  int lrow = l & 15, kq = l >> 4;
  short8 af = *(short8*)(&As[(w * 16 + lrow) * 40 + kq * 8]);
  f32x4 zero = {0.f, 0.f, 0.f, 0.f};
  f32x4 acc[16];
#pragma unroll
  for (int ni = 0; ni < 16; ni++) {
    int n = ni * 16 + lrow;
    int p = kq ^ ((n >> 1) & 3);
    short8 bfv = *(short8*)(&Ws[n * 32 + p * 8]);
    acc[ni] = __builtin_amdgcn_mfma_f32_16x16x32_bf16(af, bfv, zero, 0, 0, 0);
  }
#pragma unroll
  for (int ni = 0; ni < 16; ni++) {
    int colL = ni * 16 + lrow;
    float bv = b1[(size_t)e * NH + h * 256 + colL];
#pragma unroll
    for (int r = 0; r < 4; r++) {
      int row = w * 16 + kq * 4 + r;
      Ts[row * 264 + colL] = f2bf(acc[ni][r] + bv);
    }
  }
  __syncthreads();
#pragma unroll
  for (int i = 0; i < 8; i++) {  // coalesced a_emb rows
    int u = i * 256 + tid;
    int t = u >> 5, c4 = u & 31;
    uint4 v = *(uint4*)(&Ts[t * 264 + c4 * 8]);
    *(uint4*)(Xa + ((size_t)(b * NT + t)) * NH + h * 256 + c4 * 8) = v;
  }
  if (tid < 32) {  // tau written ONCE per sample (broadcast over T exploited)
    uint4 v = *(uint4*)(&tau[tid * 8]);
    *(uint4*)(Xt + (size_t)b * NH + h * 256 + tid * 8) = v;
  }
}

// ---------------------------------------------------------------------------
// Grouped GEMM v2: BM=128 (2 samples) x BN=64 x BK=64, 4 waves 2x2,
// all staging via global_load_lds(16B), XOR-swizzled LDS (conflict-free b128),
// LDS-transpose epilogue -> coalesced uint4 stores.
// A rows: k<512 from Xa[sample rows]; k>=512 (HASTAU) from per-sample Xt row.
// ---------------------------------------------------------------------------
template <int KTOT, bool HASTAU, bool SWISH, bool OUT_BF16>
__global__ __launch_bounds__(256) void gemm2_kernel(
    const unsigned short* __restrict__ Xa, const unsigned short* __restrict__ Xt,
    const unsigned short* __restrict__ Wt, const float* __restrict__ bias,
    void* __restrict__ Yv, const int* __restrict__ tiles,
    const int* __restrict__ pntiles) {
  constexpr int SMEM = OUT_BF16 ? 24576 : 34816;
  __shared__ __align__(16) unsigned char smem[SMEM];
  unsigned short* As = (unsigned short*)smem;            // [128][64] swizzled
  unsigned short* Bs = (unsigned short*)(smem + 16384);  // [64][64]  swizzled

  int ti = blockIdx.y;
  if (ti >= *pntiles) return;
  int n0 = blockIdx.x * 64;
  int e = tiles[3 * ti], s0 = tiles[3 * ti + 1], s1 = tiles[3 * ti + 2];
  int s1v = (s1 < 0) ? s0 : s1;

  int tid = threadIdx.x;
  int l = tid & 63;
  int wr = (tid >> 7), wc = (tid >> 6) & 1;
  int lrow = l & 15, kq = l >> 4;

  f32x4 acc[4][2];
#pragma unroll
  for (int mi = 0; mi < 4; mi++)
#pragma unroll
    for (int ni = 0; ni < 2; ni++) acc[mi][ni] = (f32x4){0.f, 0.f, 0.f, 0.f};

  const unsigned short* wbase = Wt + ((size_t)e * NH + n0) * KTOT;

  for (int it = 0; it < KTOT / 64; it++) {
    int k0 = it * 64;
    __syncthreads();
    // A: 16KB (128 rows x 64 k), 4 issues/thread
#pragma unroll
    for (int j = 0; j < 4; j++) {
      int u = j * 256 + tid;
      int row = u >> 3, p = u & 7;
      int ch = p ^ (row & 7);
      int kk = k0 + ch * 8;
      int s = (row < 64) ? s0 : s1v;
      const unsigned short* src;
      if (HASTAU && kk >= 512)
        src = Xt + (size_t)s * NH + (kk - 512);
      else
        src = Xa + ((size_t)(s * NT + (row & 63))) * NH + kk;
      gl2lds16(src, As + (size_t)(j * 256 + (tid & 448)) * 8);
    }
    // B: 8KB (64 n-rows x 64 k), 2 issues/thread
#pragma unroll
    for (int j = 0; j < 2; j++) {
      int u = j * 256 + tid;
      int n = u >> 3, p = u & 7;
      int ch = p ^ (n & 7);
      gl2lds16(wbase + (size_t)n * KTOT + k0 + ch * 8,
               Bs + (size_t)(j * 256 + (tid & 448)) * 8);
    }
    __syncthreads();

    short8 afr[2][4], bfr[2][2];
#pragma unroll
    for (int s2 = 0; s2 < 2; s2++) {
#pragma unroll
      for (int mi = 0; mi < 4; mi++) {
        int row = wr * 64 + mi * 16 + lrow;
        int p = (s2 * 4 + kq) ^ (row & 7);
        afr[s2][mi] = *(short8*)(&As[row * 64 + p * 8]);
      }
#pragma unroll
      for (int ni = 0; ni < 2; ni++) {
        int n = wc * 32 + ni * 16 + lrow;
        int p = (s2 * 4 + kq) ^ (n & 7);
        bfr[s2][ni] = *(short8*)(&Bs[n * 64 + p * 8]);
      }
    }
#pragma unroll
    for (int s2 = 0; s2 < 2; s2++)
#pragma unroll
      for (int mi = 0; mi < 4; mi++)
#pragma unroll
        for (int ni = 0; ni < 2; ni++)
          acc[mi][ni] = __builtin_amdgcn_mfma_f32_16x16x32_bf16(
              afr[s2][mi], bfr[s2][ni], acc[mi][ni], 0, 0, 0);
  }
  __syncthreads();

  // epilogue: bias(+swish) -> Ts (LDS transpose) -> coalesced stores
#pragma unroll
  for (int ni = 0; ni < 2; ni++) {
    int colL = wc * 32 + ni * 16 + lrow;
    float bv = bias[(size_t)e * NH + n0 + colL];
#pragma unroll
    for (int mi = 0; mi < 4; mi++) {
#pragma unroll
      for (int r = 0; r < 4; r++) {
        int row = wr * 64 + mi * 16 + kq * 4 + r;
        float v = acc[mi][ni][r] + bv;
        if (SWISH) v = v / (1.0f + __expf(-v));
        if (OUT_BF16)
          ((unsigned short*)smem)[row * 80 + colL] = f2bf(v);
        else
          ((float*)smem)[row * 68 + colL] = v;
      }
    }
  }
  __syncthreads();
  if (OUT_BF16) {
    unsigned short* Y = (unsigned short*)Yv;
#pragma unroll
    for (int i = 0; i < 4; i++) {
      int u = i * 256 + tid;
      int row = u >> 3, c = u & 7;
      if (row >= 64 && s1 < 0) continue;
      int s = (row < 64) ? s0 : s1;
      uint4 v = *(uint4*)(&((unsigned short*)smem)[row * 80 + c * 8]);
      *(uint4*)(Y + ((size_t)(s * NT + (row & 63))) * NH + n0 + c * 8) = v;
    }
  } else {
    float* Y = (float*)Yv;
#pragma unroll
    for (int i = 0; i < 8; i++) {
      int u = i * 256 + tid;
      int row = u >> 4, c = u & 15;
      if (row >= 64 && s1 < 0) continue;
      int s = (row < 64) ? s0 : s1;
      uint4 v = *(uint4*)(&((float*)smem)[row * 68 + c * 4]);
      *(uint4*)(Y + ((size_t)(s * NT + (row & 63))) * NH + n0 + c * 4) = v;
    }
  }
}

// ---------------------------------------------------------------------------
extern "C" void kernel_launch(void* const* d_in, const int* in_sizes, int n_in,
                              void* d_out, int out_size, void* d_ws, size_t ws_size,
                              hipStream_t stream) {
  const float* actions   = (const float*)d_in[0];
  const int*   timesteps = (const int*)d_in[1];
  const int*   cat_ids   = (const int*)d_in[2];
  const float* W1 = (const float*)d_in[3];
  const float* b1 = (const float*)d_in[4];
  const float* W2 = (const float*)d_in[5];
  const float* b2 = (const float*)d_in[6];
  const float* W3 = (const float*)d_in[7];
  const float* b3 = (const float*)d_in[8];

  // ws: Xa 16MB | H 16MB | Wt3 16MB | Wt1 1MB | Xt 256KB | tiles  (~51.7MB)
  // Wt2 (32MB bf16) lives in d_out (dead until gemm3 overwrites it).
  unsigned short* Xa  = (unsigned short*)d_ws;
  unsigned short* Hb  = (unsigned short*)((char*)d_ws + (size_t)16777216);
  unsigned short* Wt3 = (unsigned short*)((char*)d_ws + (size_t)33554432);
  unsigned short* Wt1 = (unsigned short*)((char*)d_ws + (size_t)50331648);
  unsigned short* Xt  = (unsigned short*)((char*)d_ws + (size_t)51380224);
  int* tiles  = (int*)((char*)d_ws + (size_t)51642368);
  int* ntiles = tiles + 3 * MAXTILES;
  unsigned short* Wt2 = (unsigned short*)d_out;  // exact 32MB fit

  groupk<<<1, 256, 0, stream>>>(cat_ids, tiles, ntiles);
  prep_kernel<<<dim3(8, 1, NE), 256, 0, stream>>>(W1, Wt1, NA);
  prep_kernel<<<dim3(8, 16, NE), 256, 0, stream>>>(W2, Wt2, 1024);
  prep_kernel<<<dim3(8, 8, NE), 256, 0, stream>>>(W3, Wt3, 512);
  buildx2_kernel<<<dim3(2, NB), 256, 0, stream>>>(actions, timesteps, cat_ids,
                                                  Wt1, b1, Xa, Xt);
  gemm2_kernel<1024, true, true, true><<<dim3(8, MAXTILES), 256, 0, stream>>>(
      Xa, Xt, Wt2, b2, (void*)Hb, tiles, ntiles);
  gemm2_kernel<512, false, false, false><<<dim3(8, MAXTILES), 256, 0, stream>>>(
      Hb, nullptr, Wt3, b3, d_out, tiles, ntiles);
}